// Round 6
// baseline (318.965 us; speedup 1.0000x reference)
//
#include <hip/hip_runtime.h>
#include <hip/hip_bf16.h>

#define NN   50000
#define EE   800000
#define INF_ 128
#define HH   16
#define OUTC 300
#define SB   196   // scan blocks: 196*256 = 50176 >= NN

// converted-weight offsets (words) inside wc
#define W1_OFF   0
#define WL1_OFF  2048
#define B1_OFF   4096
#define BL1_OFF  4112
#define W2_OFF   4128
#define WL2_OFF  4384
#define B2_OFF   4640
#define BL2_OFF  4656
#define WO_OFF   4672
#define BO_OFF   9472
#define WC_TOT   9772

__device__ __forceinline__ float bfu2f(unsigned short u) {
    return __uint_as_float(((unsigned)u) << 16);
}

__device__ __forceinline__ float cvt1(const void* p, int i, int flag) {
    return flag ? ((const float*)p)[i] : bfu2f(((const unsigned short*)p)[i]);
}

// ---- dtype detect: scan low-half-bf16 of first 256 words of x ----
__global__ __launch_bounds__(64) void detect_kernel(const unsigned* __restrict__ xw, int* __restrict__ flag) {
    int t = threadIdx.x;
    int hits = 0;
#pragma unroll
    for (int q = 0; q < 4; q++) {
        unsigned w = xw[t * 4 + q];
        float lo = __uint_as_float(w << 16);
        if (!(fabsf(lo) < 1e4f)) hits++;
    }
#pragma unroll
    for (int o = 32; o > 0; o >>= 1) hits += __shfl_xor(hits, o);
    if (t == 0) flag[0] = (hits > 8) ? 1 : 0;   // 1 => inputs are fp32
}

// ---- convert all weights/biases to fp32 in ws ----
__global__ __launch_bounds__(256) void convert_kernel(
    const void* __restrict__ W1, const void* __restrict__ Wl1,
    const void* __restrict__ b1, const void* __restrict__ bl1,
    const void* __restrict__ W2, const void* __restrict__ Wl2,
    const void* __restrict__ b2, const void* __restrict__ bl2,
    const void* __restrict__ Wo, const void* __restrict__ bo,
    const int* __restrict__ flagp, float* __restrict__ wc)
{
    int t = blockIdx.x * 256 + threadIdx.x;
    if (t >= WC_TOT) return;
    const int flag = flagp[0];
    float v;
    if      (t < WL1_OFF) v = cvt1(W1,  t - W1_OFF,  flag);
    else if (t < B1_OFF)  v = cvt1(Wl1, t - WL1_OFF, flag);
    else if (t < BL1_OFF) v = cvt1(b1,  t - B1_OFF,  flag);
    else if (t < W2_OFF)  v = cvt1(bl1, t - BL1_OFF, flag);
    else if (t < WL2_OFF) v = cvt1(W2,  t - W2_OFF,  flag);
    else if (t < B2_OFF)  v = cvt1(Wl2, t - WL2_OFF, flag);
    else if (t < BL2_OFF) v = cvt1(b2,  t - B2_OFF,  flag);
    else if (t < WO_OFF)  v = cvt1(bl2, t - BL2_OFF, flag);
    else if (t < BO_OFF)  v = cvt1(Wo,  t - WO_OFF,  flag);
    else                  v = cvt1(bo,  t - BO_OFF,  flag);
    wc[t] = v;
}

// ---- histogram of dst ----
__global__ __launch_bounds__(256) void count_kernel(const int* __restrict__ dst, int* __restrict__ cnt) {
    int e = blockIdx.x * 256 + threadIdx.x;
    if (e < EE) atomicAdd(&cnt[dst[e]], 1);
}

// ---- hierarchical scan stage 1 ----
__global__ __launch_bounds__(256) void scan1_kernel(
    const int* __restrict__ cnt, int* __restrict__ off, int* __restrict__ bsum)
{
    __shared__ int sd[256];
    int t = threadIdx.x;
    int i = blockIdx.x * 256 + t;
    int v = (i < NN) ? cnt[i] : 0;
    sd[t] = v;
    __syncthreads();
    for (int d = 1; d < 256; d <<= 1) {
        int u = (t >= d) ? sd[t - d] : 0;
        __syncthreads();
        sd[t] += u;
        __syncthreads();
    }
    if (i < NN) off[i] = sd[t] - v;
    if (t == 255) bsum[blockIdx.x] = sd[255];
}

// ---- stage 2: scan block sums ----
__global__ __launch_bounds__(256) void scan2_kernel(const int* __restrict__ bsum, int* __restrict__ boff) {
    __shared__ int sd[256];
    int t = threadIdx.x;
    int v = (t < SB) ? bsum[t] : 0;
    sd[t] = v;
    __syncthreads();
    for (int d = 1; d < 256; d <<= 1) {
        int u = (t >= d) ? sd[t - d] : 0;
        __syncthreads();
        sd[t] += u;
        __syncthreads();
    }
    if (t < SB) boff[t] = sd[t] - v;
}

// ---- stage 3: add block offsets + dinv ----
__global__ __launch_bounds__(256) void scan3_kernel(
    const int* __restrict__ cnt, int* __restrict__ off,
    const int* __restrict__ boff, float* __restrict__ dinv)
{
    int i = blockIdx.x * 256 + threadIdx.x;
    if (i < NN) {
        off[i] += boff[blockIdx.x];
        dinv[i] = rsqrtf((float)cnt[i] + 1.0f);
    }
    if (i == NN) off[NN] = EE;
}

// ---- placement ----
__global__ __launch_bounds__(256) void place_kernel(
    const int* __restrict__ src, const int* __restrict__ dst,
    const int* __restrict__ off, int* __restrict__ cur, int* __restrict__ csr_src)
{
    int e = blockIdx.x * 256 + threadIdx.x;
    if (e >= EE) return;
    int d = dst[e];
    int p = off[d] + atomicAdd(&cur[d], 1);
    csr_src[p] = src[e];
}

// ---- layer1 linear: A = (x@W1)*dinv, B = x@Wl1 + bl1 (scalar-cache weights) ----
__global__ __launch_bounds__(256) void lin1_kernel(
    const void* __restrict__ xp, const float* __restrict__ wc,
    const float* __restrict__ dinv, const int* __restrict__ flagp,
    float* __restrict__ A, float* __restrict__ B)
{
    const float* __restrict__ W1c  = wc + W1_OFF;
    const float* __restrict__ Wl1c = wc + WL1_OFF;
    const float* __restrict__ bl1c = wc + BL1_OFF;

    int i = blockIdx.x * 256 + threadIdx.x;
    if (i >= NN) return;
    const int flag = flagp[0];

    float a[HH], l[HH];
#pragma unroll
    for (int f = 0; f < HH; f++) { a[f] = 0.f; l[f] = 0.f; }

    for (int k0 = 0; k0 < INF_ / 8; k0++) {
        float xv[8];
        if (flag) {
            const float4* xr = (const float4*)((const float*)xp + (size_t)i * INF_);
            float4 r0 = xr[k0 * 2], r1 = xr[k0 * 2 + 1];
            xv[0] = r0.x; xv[1] = r0.y; xv[2] = r0.z; xv[3] = r0.w;
            xv[4] = r1.x; xv[5] = r1.y; xv[6] = r1.z; xv[7] = r1.w;
        } else {
            const uint4* xr = (const uint4*)((const unsigned short*)xp + (size_t)i * INF_);
            uint4 v = xr[k0];
            unsigned uu[4] = { v.x, v.y, v.z, v.w };
#pragma unroll
            for (int q = 0; q < 4; q++) {
                xv[q * 2]     = __uint_as_float(uu[q] << 16);
                xv[q * 2 + 1] = __uint_as_float(uu[q] & 0xffff0000u);
            }
        }
#pragma unroll
        for (int j = 0; j < 8; j++) {
            float xj = xv[j];
            int k = k0 * 8 + j;   // uniform: scalar loads for weights
#pragma unroll
            for (int f = 0; f < HH; f++) {
                a[f] = fmaf(xj, W1c[k * HH + f], a[f]);
                l[f] = fmaf(xj, Wl1c[k * HH + f], l[f]);
            }
        }
    }
    float di = dinv[i];
#pragma unroll
    for (int f = 0; f < HH; f++) {
        A[i * HH + f] = a[f] * di;
        B[i * HH + f] = l[f] + bl1c[f];
    }
}

// ---- fused gather + combine, 16-edge-parallel (fp32 bias from wc).
// mode 0: Y[i] = relu(di*(agg + X[i]) + b) + Y[i]
// mode 1: Y[i] = (relu(di*(agg + X[i]) + b) + Y[i]) * di
// mode 2: Y[i] = di*(agg + X[i])
__global__ __launch_bounds__(256) void gather_combine_kernel(
    const int* __restrict__ off, const int* __restrict__ csr,
    const float* __restrict__ dinv, const float* __restrict__ X,
    float* __restrict__ Y, const float* __restrict__ bias, int mode)
{
    int wid = (blockIdx.x * 256 + threadIdx.x) >> 6;   // node id
    int lane = threadIdx.x & 63;
    if (wid >= NN) return;
    int e = lane >> 2, q = lane & 3;
    int s0 = off[wid], s1 = off[wid + 1];
    float4 acc = make_float4(0.f, 0.f, 0.f, 0.f);
    for (int base = s0; base < s1; base += 16) {
        int p = base + e;
        bool valid = (p < s1);
        int s = valid ? csr[p] : 0;
        float4 v = ((const float4*)X)[(size_t)s * 4 + q];
        if (valid) { acc.x += v.x; acc.y += v.y; acc.z += v.z; acc.w += v.w; }
    }
#pragma unroll
    for (int m = 4; m <= 32; m <<= 1) {
        acc.x += __shfl_xor(acc.x, m);
        acc.y += __shfl_xor(acc.y, m);
        acc.z += __shfl_xor(acc.z, m);
        acc.w += __shfl_xor(acc.w, m);
    }
    if (lane < 4) {    // lane == q: handles features q*4 .. q*4+3
        float di = dinv[wid];
        float4 xr = ((const float4*)X)[(size_t)wid * 4 + lane];
        float4 r;
        if (mode == 2) {
            r.x = di * (acc.x + xr.x);
            r.y = di * (acc.y + xr.y);
            r.z = di * (acc.z + xr.z);
            r.w = di * (acc.w + xr.w);
        } else {
            float4 yr = ((const float4*)Y)[(size_t)wid * 4 + lane];
            float o0 = fmaxf(di * (acc.x + xr.x) + bias[lane * 4 + 0], 0.f) + yr.x;
            float o1 = fmaxf(di * (acc.y + xr.y) + bias[lane * 4 + 1], 0.f) + yr.y;
            float o2 = fmaxf(di * (acc.z + xr.z) + bias[lane * 4 + 2], 0.f) + yr.z;
            float o3 = fmaxf(di * (acc.w + xr.w) + bias[lane * 4 + 3], 0.f) + yr.w;
            if (mode) { o0 *= di; o1 *= di; o2 *= di; o3 *= di; }
            r = make_float4(o0, o1, o2, o3);
        }
        ((float4*)Y)[(size_t)wid * 4 + lane] = r;
    }
}

// ---- layer2 linear (scalar-cache weights) ----
__global__ __launch_bounds__(256) void lin2_kernel(
    float* __restrict__ B, const float* __restrict__ wc,
    const float* __restrict__ dinv, float* __restrict__ A)
{
    const float* __restrict__ W2c  = wc + W2_OFF;
    const float* __restrict__ Wl2c = wc + WL2_OFF;
    const float* __restrict__ bl2c = wc + BL2_OFF;

    int i = blockIdx.x * 256 + threadIdx.x;
    if (i >= NN) return;

    float z[HH];
    const float4* dr = (const float4*)(B + (size_t)i * HH);
#pragma unroll
    for (int q = 0; q < 4; q++) {
        float4 r = dr[q];
        z[q * 4 + 0] = r.x; z[q * 4 + 1] = r.y; z[q * 4 + 2] = r.z; z[q * 4 + 3] = r.w;
    }
    float a[HH], l[HH];
#pragma unroll
    for (int f = 0; f < HH; f++) { a[f] = 0.f; l[f] = 0.f; }
#pragma unroll
    for (int k = 0; k < HH; k++) {
        float zk = z[k];
#pragma unroll
        for (int f = 0; f < HH; f++) {
            a[f] = fmaf(zk, W2c[k * HH + f], a[f]);
            l[f] = fmaf(zk, Wl2c[k * HH + f], l[f]);
        }
    }
    float di = dinv[i];
#pragma unroll
    for (int f = 0; f < HH; f++) {
        A[i * HH + f] = a[f] * di;
        B[i * HH + f] = l[f] + bl2c[f];
    }
}

// ---- final (streaming, 4 nodes per wave simultaneously):
//      y = z@Wo + bo, log_softmax, dual-dtype out ----
__global__ __launch_bounds__(256) void final_kernel(
    const float* __restrict__ Z, const float* __restrict__ wc,
    const int* __restrict__ flagp, void* __restrict__ outp)
{
    __shared__ float sW[HH * OUTC];   // 19.2 KB
    __shared__ float sbb[OUTC];
    const float* __restrict__ Woc = wc + WO_OFF;
    const float* __restrict__ boc = wc + BO_OFF;
    for (int t = threadIdx.x; t < HH * OUTC; t += 256) sW[t] = Woc[t];
    for (int t = threadIdx.x; t < OUTC; t += 256)      sbb[t] = boc[t];
    __syncthreads();

    const int flag = flagp[0];
    int wave = threadIdx.x >> 6, lane = threadIdx.x & 63;
    int i0 = blockIdx.x * 16 + wave * 4;    // 3125 blocks * 16 = 50000 exact

    // load z fragment for 4 nodes: lanes 0..15 hold the 16 features
    float zf[4];
#pragma unroll
    for (int n = 0; n < 4; n++) zf[n] = Z[(size_t)(i0 + n) * HH + (lane & 15)];

    float y[4][5];
    float bb[5];
#pragma unroll
    for (int jj = 0; jj < 5; jj++) {
        int j = lane + jj * 64;
        bb[jj] = (j < OUTC) ? sbb[j] : 0.f;
#pragma unroll
        for (int n = 0; n < 4; n++) y[n][jj] = bb[jj];
    }

    // single sweep over weights: each sW element read ONCE, 4 FMAs per read
#pragma unroll
    for (int k = 0; k < HH; k++) {
        float zb[4];
#pragma unroll
        for (int n = 0; n < 4; n++) zb[n] = __shfl(zf[n], k);
#pragma unroll
        for (int jj = 0; jj < 5; jj++) {
            int j = lane + jj * 64;
            float w = (j < OUTC) ? sW[k * OUTC + j] : 0.f;
#pragma unroll
            for (int n = 0; n < 4; n++) y[n][jj] = fmaf(zb[n], w, y[n][jj]);
        }
    }

    // softmax per node
#pragma unroll
    for (int n = 0; n < 4; n++) {
        float m = -1e30f;
#pragma unroll
        for (int jj = 0; jj < 5; jj++) {
            int j = lane + jj * 64;
            if (j < OUTC) m = fmaxf(m, y[n][jj]);
        }
#pragma unroll
        for (int o = 32; o > 0; o >>= 1) m = fmaxf(m, __shfl_xor(m, o));
        float s = 0.f;
#pragma unroll
        for (int jj = 0; jj < 5; jj++) {
            int j = lane + jj * 64;
            if (j < OUTC) s += __expf(y[n][jj] - m);
        }
#pragma unroll
        for (int o = 32; o > 0; o >>= 1) s += __shfl_xor(s, o);
        float lse = m + __logf(s);
#pragma unroll
        for (int jj = 0; jj < 5; jj++) {
            int j = lane + jj * 64;
            if (j < OUTC) {
                float v = y[n][jj] - lse;
                size_t ofs = (size_t)(i0 + n) * OUTC + j;
                if (flag) ((float*)outp)[ofs] = v;
                else      ((__hip_bfloat16*)outp)[ofs] = __float2bfloat16(v);
            }
        }
    }
}

extern "C" void kernel_launch(void* const* d_in, const int* in_sizes, int n_in,
                              void* d_out, int out_size, void* d_ws, size_t ws_size,
                              hipStream_t stream) {
    const void* x   = d_in[0];
    const int*  ei  = (const int*)d_in[1];
    const void* W1  = d_in[2];
    const void* b1  = d_in[3];
    const void* Wl1 = d_in[4];
    const void* bl1 = d_in[5];
    const void* W2  = d_in[6];
    const void* b2  = d_in[7];
    const void* Wl2 = d_in[8];
    const void* bl2 = d_in[9];
    const void* Wo  = d_in[10];
    const void* bo  = d_in[11];

    const int* srcp = ei;        // edge_index[0]
    const int* dstp = ei + EE;   // edge_index[1]

    // ws layout (4-byte words), 16B-aligned regions:
    char* wsb = (char*)d_ws;
    int*   flag    = (int*)wsb;                        // 0..3
    float* wc      = (float*)(wsb + 4 * 16);           // 16 .. 9788  (converted weights)
    int*   cnt     = (int*)(wsb + 4 * 10000);          // 10000 .. 60000
    int*   off     = (int*)(wsb + 4 * 60000);          // 60000 .. 110001
    int*   bsum    = (int*)(wsb + 4 * 110004);         // +196
    int*   boff    = (int*)(wsb + 4 * 110208);         // +196
    int*   csr_src = (int*)(wsb + 4 * 110400);         // .. 910400
    float* dinv    = (float*)(wsb + 4 * 910400);       // .. 960400
    float* A       = (float*)(wsb + 4 * 960400);       // .. 1760400
    float* B       = (float*)(wsb + 4 * 1760400);      // .. 2560400 (~10.2 MB)

    const int gE = (EE + 255) / 256;
    const int gN = (NN + 255) / 256;
    const int gG = (NN * 64 + 255) / 256;   // wave-per-node gathers
    const int gW = (WC_TOT + 255) / 256;

    // dtype detect + weight conversion
    detect_kernel<<<1, 64, 0, stream>>>((const unsigned*)x, flag);
    convert_kernel<<<gW, 256, 0, stream>>>(W1, Wl1, b1, bl1, W2, Wl2, b2, bl2,
                                           Wo, bo, flag, wc);

    // CSR build + dinv (hierarchical scan)
    hipMemsetAsync(cnt, 0, NN * sizeof(int), stream);
    count_kernel<<<gE, 256, 0, stream>>>(dstp, cnt);
    scan1_kernel<<<SB, 256, 0, stream>>>(cnt, off, bsum);
    scan2_kernel<<<1, 256, 0, stream>>>(bsum, boff);
    scan3_kernel<<<SB, 256, 0, stream>>>(cnt, off, boff, dinv);
    hipMemsetAsync(cnt, 0, NN * sizeof(int), stream);   // reuse cnt as cursor
    place_kernel<<<gE, 256, 0, stream>>>(srcp, dstp, off, cnt, csr_src);

    // layer 1: lin -> gather+combine (B <- h1)
    lin1_kernel<<<gN, 256, 0, stream>>>(x, wc, dinv, flag, A, B);
    gather_combine_kernel<<<gG, 256, 0, stream>>>(off, csr_src, dinv, A, B, wc + B1_OFF, 0);

    // layer 2: lin -> gather+combine (B <- out2*dinv)
    lin2_kernel<<<gN, 256, 0, stream>>>(B, wc, dinv, A);
    gather_combine_kernel<<<gG, 256, 0, stream>>>(off, csr_src, dinv, A, B, wc + B2_OFF, 1);

    // output aggregation: A <- z = dinv*(agg(B) + B)
    gather_combine_kernel<<<gG, 256, 0, stream>>>(off, csr_src, dinv, B, A, wc + B2_OFF, 2);

    // final matmul + log_softmax (streaming, 4-node-batched)
    final_kernel<<<(NN + 15) / 16, 256, 0, stream>>>(A, wc, flag, d_out);
}

// Round 8
// 312.202 us; speedup vs baseline: 1.0217x; 1.0217x over previous
//
#include <hip/hip_runtime.h>
#include <hip/hip_bf16.h>

#define NN   50000
#define EE   800000
#define INF_ 128
#define HH   16
#define OUTC 300
#define SB   196   // scan blocks: 196*256 = 50176 >= NN

// converted-weight offsets (words) inside wc
#define W1_OFF   0
#define WL1_OFF  2048
#define B1_OFF   4096
#define BL1_OFF  4112
#define W2_OFF   4128
#define WL2_OFF  4384
#define B2_OFF   4640
#define BL2_OFF  4656
#define WO_OFF   4672
#define BO_OFF   9472
#define WC_TOT   9772

__device__ __forceinline__ float bfu2f(unsigned short u) {
    return __uint_as_float(((unsigned)u) << 16);
}
__device__ __forceinline__ unsigned short f2bfu(float f) {
    __hip_bfloat16 h = __float2bfloat16(f);
    return *reinterpret_cast<unsigned short*>(&h);
}
// pack two bf16 (lo = feature 2j, hi = feature 2j+1) into a uint
__device__ __forceinline__ unsigned packbf(float lo, float hi) {
    return (unsigned)f2bfu(lo) | ((unsigned)f2bfu(hi) << 16);
}

__device__ __forceinline__ float cvt1(const void* p, int i, int flag) {
    return flag ? ((const float*)p)[i] : bfu2f(((const unsigned short*)p)[i]);
}

// ---- dtype detect ----
__global__ __launch_bounds__(64) void detect_kernel(const unsigned* __restrict__ xw, int* __restrict__ flag) {
    int t = threadIdx.x;
    int hits = 0;
#pragma unroll
    for (int q = 0; q < 4; q++) {
        unsigned w = xw[t * 4 + q];
        float lo = __uint_as_float(w << 16);
        if (!(fabsf(lo) < 1e4f)) hits++;
    }
#pragma unroll
    for (int o = 32; o > 0; o >>= 1) hits += __shfl_xor(hits, o);
    if (t == 0) flag[0] = (hits > 8) ? 1 : 0;   // 1 => inputs are fp32
}

// ---- convert all weights/biases to fp32 in ws ----
__global__ __launch_bounds__(256) void convert_kernel(
    const void* __restrict__ W1, const void* __restrict__ Wl1,
    const void* __restrict__ b1, const void* __restrict__ bl1,
    const void* __restrict__ W2, const void* __restrict__ Wl2,
    const void* __restrict__ b2, const void* __restrict__ bl2,
    const void* __restrict__ Wo, const void* __restrict__ bo,
    const int* __restrict__ flagp, float* __restrict__ wc)
{
    int t = blockIdx.x * 256 + threadIdx.x;
    if (t >= WC_TOT) return;
    const int flag = flagp[0];
    float v;
    if      (t < WL1_OFF) v = cvt1(W1,  t - W1_OFF,  flag);
    else if (t < B1_OFF)  v = cvt1(Wl1, t - WL1_OFF, flag);
    else if (t < BL1_OFF) v = cvt1(b1,  t - B1_OFF,  flag);
    else if (t < W2_OFF)  v = cvt1(bl1, t - BL1_OFF, flag);
    else if (t < WL2_OFF) v = cvt1(W2,  t - W2_OFF,  flag);
    else if (t < B2_OFF)  v = cvt1(Wl2, t - WL2_OFF, flag);
    else if (t < BL2_OFF) v = cvt1(b2,  t - B2_OFF,  flag);
    else if (t < WO_OFF)  v = cvt1(bl2, t - BL2_OFF, flag);
    else if (t < BO_OFF)  v = cvt1(Wo,  t - WO_OFF,  flag);
    else                  v = cvt1(bo,  t - BO_OFF,  flag);
    wc[t] = v;
}

// ---- histogram of dst ----
__global__ __launch_bounds__(256) void count_kernel(const int* __restrict__ dst, int* __restrict__ cnt) {
    int e = blockIdx.x * 256 + threadIdx.x;
    if (e < EE) atomicAdd(&cnt[dst[e]], 1);
}

// ---- hierarchical scan stage 1 ----
__global__ __launch_bounds__(256) void scan1_kernel(
    const int* __restrict__ cnt, int* __restrict__ off, int* __restrict__ bsum)
{
    __shared__ int sd[256];
    int t = threadIdx.x;
    int i = blockIdx.x * 256 + t;
    int v = (i < NN) ? cnt[i] : 0;
    sd[t] = v;
    __syncthreads();
    for (int d = 1; d < 256; d <<= 1) {
        int u = (t >= d) ? sd[t - d] : 0;
        __syncthreads();
        sd[t] += u;
        __syncthreads();
    }
    if (i < NN) off[i] = sd[t] - v;
    if (t == 255) bsum[blockIdx.x] = sd[255];
}

// ---- stage 2: scan block sums ----
__global__ __launch_bounds__(256) void scan2_kernel(const int* __restrict__ bsum, int* __restrict__ boff) {
    __shared__ int sd[256];
    int t = threadIdx.x;
    int v = (t < SB) ? bsum[t] : 0;
    sd[t] = v;
    __syncthreads();
    for (int d = 1; d < 256; d <<= 1) {
        int u = (t >= d) ? sd[t - d] : 0;
        __syncthreads();
        sd[t] += u;
        __syncthreads();
    }
    if (t < SB) boff[t] = sd[t] - v;
}

// ---- stage 3: add block offsets + dinv + zero cursor (saves a memset) ----
__global__ __launch_bounds__(256) void scan3_kernel(
    int* __restrict__ cnt, int* __restrict__ off,
    const int* __restrict__ boff, float* __restrict__ dinv)
{
    int i = blockIdx.x * 256 + threadIdx.x;
    if (i < NN) {
        off[i] += boff[blockIdx.x];
        dinv[i] = rsqrtf((float)cnt[i] + 1.0f);
        cnt[i] = 0;                       // cursor for place
    }
    if (i == NN) off[NN] = EE;
}

// ---- placement ----
__global__ __launch_bounds__(256) void place_kernel(
    const int* __restrict__ src, const int* __restrict__ dst,
    const int* __restrict__ off, int* __restrict__ cur, int* __restrict__ csr_src)
{
    int e = blockIdx.x * 256 + threadIdx.x;
    if (e >= EE) return;
    int d = dst[e];
    int p = off[d] + atomicAdd(&cur[d], 1);
    csr_src[p] = src[e];
}

// ---- layer1 linear: A = bf16((x@W1)*dinv), B = bf16(x@Wl1 + bl1) ----
__global__ __launch_bounds__(256) void lin1_kernel(
    const void* __restrict__ xp, const float* __restrict__ wc,
    const float* __restrict__ dinv, const int* __restrict__ flagp,
    unsigned short* __restrict__ A, unsigned short* __restrict__ B)
{
    __shared__ float2 sWL[INF_ * HH];   // .x = W1, .y = Wl1
    __shared__ float sb[HH];
    for (int t = threadIdx.x; t < INF_ * HH; t += 256)
        sWL[t] = make_float2(wc[W1_OFF + t], wc[WL1_OFF + t]);
    if (threadIdx.x < HH) sb[threadIdx.x] = wc[BL1_OFF + threadIdx.x];
    __syncthreads();

    int i = blockIdx.x * 256 + threadIdx.x;
    if (i >= NN) return;
    const int flag = flagp[0];

    float a[HH], l[HH];
#pragma unroll
    for (int f = 0; f < HH; f++) { a[f] = 0.f; l[f] = 0.f; }

    for (int k0 = 0; k0 < INF_ / 8; k0++) {
        float xv[8];
        if (flag) {
            const float4* xr = (const float4*)((const float*)xp + (size_t)i * INF_);
            float4 r0 = xr[k0 * 2], r1 = xr[k0 * 2 + 1];
            xv[0] = r0.x; xv[1] = r0.y; xv[2] = r0.z; xv[3] = r0.w;
            xv[4] = r1.x; xv[5] = r1.y; xv[6] = r1.z; xv[7] = r1.w;
        } else {
            const uint4* xr = (const uint4*)((const unsigned short*)xp + (size_t)i * INF_);
            uint4 v = xr[k0];
            unsigned uu[4] = { v.x, v.y, v.z, v.w };
#pragma unroll
            for (int q = 0; q < 4; q++) {
                xv[q * 2]     = __uint_as_float(uu[q] << 16);
                xv[q * 2 + 1] = __uint_as_float(uu[q] & 0xffff0000u);
            }
        }
#pragma unroll
        for (int j = 0; j < 8; j++) {
            float xj = xv[j];
            int k = k0 * 8 + j;
#pragma unroll
            for (int f = 0; f < HH; f++) {
                float2 wv = sWL[k * HH + f];
                a[f] = fmaf(xj, wv.x, a[f]);
                l[f] = fmaf(xj, wv.y, l[f]);
            }
        }
    }
    float di = dinv[i];
    unsigned pa[8], pb[8];
#pragma unroll
    for (int h = 0; h < 8; h++) {
        pa[h] = packbf(a[2 * h] * di, a[2 * h + 1] * di);
        pb[h] = packbf(l[2 * h] + sb[2 * h], l[2 * h + 1] + sb[2 * h + 1]);
    }
    uint4* Ar = (uint4*)(A + (size_t)i * HH);
    uint4* Br = (uint4*)(B + (size_t)i * HH);
    Ar[0] = make_uint4(pa[0], pa[1], pa[2], pa[3]);
    Ar[1] = make_uint4(pa[4], pa[5], pa[6], pa[7]);
    Br[0] = make_uint4(pb[0], pb[1], pb[2], pb[3]);
    Br[1] = make_uint4(pb[4], pb[5], pb[6], pb[7]);
}

// ---- fused gather + combine on bf16 rows (32 B/row).
// Wave: 16 edges x 4 lanes; lane q loads uint2 (4 bf16) = features q*4..q*4+3.
// mode 0: Y[i] = bf16( relu(di*(agg + X[i]) + b) + Y[i] )
// mode 1: Y[i] = bf16( (relu(di*(agg + X[i]) + b) + Y[i]) * di )
// mode 2: Y[i] = bf16( di*(agg + X[i]) )
__global__ __launch_bounds__(256) void gather_combine_kernel(
    const int* __restrict__ off, const int* __restrict__ csr,
    const float* __restrict__ dinv, const unsigned short* __restrict__ X,
    unsigned short* __restrict__ Y, const float* __restrict__ bias, int mode)
{
    int wid = (blockIdx.x * 256 + threadIdx.x) >> 6;   // node id
    int lane = threadIdx.x & 63;
    if (wid >= NN) return;
    int e = lane >> 2, q = lane & 3;
    int s0 = off[wid], s1 = off[wid + 1];
    float a0 = 0.f, a1 = 0.f, a2 = 0.f, a3 = 0.f;
    for (int base = s0; base < s1; base += 16) {
        int p = base + e;
        bool valid = (p < s1);
        int s = valid ? csr[p] : 0;
        uint2 v = ((const uint2*)X)[(size_t)s * 4 + q];   // 8 B of 32 B row
        if (valid) {
            a0 += __uint_as_float(v.x << 16);
            a1 += __uint_as_float(v.x & 0xffff0000u);
            a2 += __uint_as_float(v.y << 16);
            a3 += __uint_as_float(v.y & 0xffff0000u);
        }
    }
#pragma unroll
    for (int m = 4; m <= 32; m <<= 1) {
        a0 += __shfl_xor(a0, m);
        a1 += __shfl_xor(a1, m);
        a2 += __shfl_xor(a2, m);
        a3 += __shfl_xor(a3, m);
    }
    if (lane < 4) {    // lane == q: features q*4 .. q*4+3
        float di = dinv[wid];
        uint2 xv = ((const uint2*)X)[(size_t)wid * 4 + lane];
        float x0 = __uint_as_float(xv.x << 16);
        float x1 = __uint_as_float(xv.x & 0xffff0000u);
        float x2 = __uint_as_float(xv.y << 16);
        float x3 = __uint_as_float(xv.y & 0xffff0000u);
        float o0, o1, o2, o3;
        if (mode == 2) {
            o0 = di * (a0 + x0); o1 = di * (a1 + x1);
            o2 = di * (a2 + x2); o3 = di * (a3 + x3);
        } else {
            uint2 yv = ((const uint2*)Y)[(size_t)wid * 4 + lane];
            float y0 = __uint_as_float(yv.x << 16);
            float y1 = __uint_as_float(yv.x & 0xffff0000u);
            float y2 = __uint_as_float(yv.y << 16);
            float y3 = __uint_as_float(yv.y & 0xffff0000u);
            o0 = fmaxf(di * (a0 + x0) + bias[lane * 4 + 0], 0.f) + y0;
            o1 = fmaxf(di * (a1 + x1) + bias[lane * 4 + 1], 0.f) + y1;
            o2 = fmaxf(di * (a2 + x2) + bias[lane * 4 + 2], 0.f) + y2;
            o3 = fmaxf(di * (a3 + x3) + bias[lane * 4 + 3], 0.f) + y3;
            if (mode) { o0 *= di; o1 *= di; o2 *= di; o3 *= di; }
        }
        ((uint2*)Y)[(size_t)wid * 4 + lane] = make_uint2(packbf(o0, o1), packbf(o2, o3));
    }
}

// ---- layer2 linear: reads h1 (bf16) from B; A = bf16((h1@W2)*dinv), B = bf16(h1@Wl2 + bl2) ----
__global__ __launch_bounds__(256) void lin2_kernel(
    unsigned short* __restrict__ B, const float* __restrict__ wc,
    const float* __restrict__ dinv, unsigned short* __restrict__ A)
{
    __shared__ float2 sWL[HH * HH];
    __shared__ float sb[HH];
    for (int t = threadIdx.x; t < HH * HH; t += 256)
        sWL[t] = make_float2(wc[W2_OFF + t], wc[WL2_OFF + t]);
    if (threadIdx.x < HH) sb[threadIdx.x] = wc[BL2_OFF + threadIdx.x];
    __syncthreads();

    int i = blockIdx.x * 256 + threadIdx.x;
    if (i >= NN) return;

    float z[HH];
    const uint4* br = (const uint4*)(B + (size_t)i * HH);
    uint4 r0 = br[0], r1 = br[1];
    unsigned uu[8] = { r0.x, r0.y, r0.z, r0.w, r1.x, r1.y, r1.z, r1.w };
#pragma unroll
    for (int h = 0; h < 8; h++) {
        z[2 * h]     = __uint_as_float(uu[h] << 16);
        z[2 * h + 1] = __uint_as_float(uu[h] & 0xffff0000u);
    }
    float a[HH], l[HH];
#pragma unroll
    for (int f = 0; f < HH; f++) { a[f] = 0.f; l[f] = 0.f; }
#pragma unroll
    for (int k = 0; k < HH; k++) {
        float zk = z[k];
#pragma unroll
        for (int f = 0; f < HH; f++) {
            float2 wv = sWL[k * HH + f];
            a[f] = fmaf(zk, wv.x, a[f]);
            l[f] = fmaf(zk, wv.y, l[f]);
        }
    }
    float di = dinv[i];
    unsigned pa[8], pb[8];
#pragma unroll
    for (int h = 0; h < 8; h++) {
        pa[h] = packbf(a[2 * h] * di, a[2 * h + 1] * di);
        pb[h] = packbf(l[2 * h] + sb[2 * h], l[2 * h + 1] + sb[2 * h + 1]);
    }
    uint4* Ar = (uint4*)(A + (size_t)i * HH);
    uint4* Br = (uint4*)(B + (size_t)i * HH);
    Ar[0] = make_uint4(pa[0], pa[1], pa[2], pa[3]);
    Ar[1] = make_uint4(pa[4], pa[5], pa[6], pa[7]);
    Br[0] = make_uint4(pb[0], pb[1], pb[2], pb[3]);
    Br[1] = make_uint4(pb[4], pb[5], pb[6], pb[7]);
}

// ---- final (streaming, 4 nodes per wave): y = z@Wo + bo, log_softmax ----
__global__ __launch_bounds__(256) void final_kernel(
    const unsigned short* __restrict__ Z, const float* __restrict__ wc,
    const int* __restrict__ flagp, void* __restrict__ outp)
{
    __shared__ float sW[HH * OUTC];   // 19.2 KB
    __shared__ float sbb[OUTC];
    for (int t = threadIdx.x; t < HH * OUTC; t += 256) sW[t] = wc[WO_OFF + t];
    for (int t = threadIdx.x; t < OUTC; t += 256)      sbb[t] = wc[BO_OFF + t];
    __syncthreads();

    const int flag = flagp[0];
    int wave = threadIdx.x >> 6, lane = threadIdx.x & 63;
    int i0 = blockIdx.x * 16 + wave * 4;    // 3125 blocks * 16 = 50000 exact

    float zf[4];
#pragma unroll
    for (int n = 0; n < 4; n++) zf[n] = bfu2f(Z[(size_t)(i0 + n) * HH + (lane & 15)]);

    float y[4][5];
#pragma unroll
    for (int jj = 0; jj < 5; jj++) {
        int j = lane + jj * 64;
        float b = (j < OUTC) ? sbb[j] : 0.f;
#pragma unroll
        for (int n = 0; n < 4; n++) y[n][jj] = b;
    }

#pragma unroll
    for (int k = 0; k < HH; k++) {
        float zb[4];
#pragma unroll
        for (int n = 0; n < 4; n++) zb[n] = __shfl(zf[n], k);
#pragma unroll
        for (int jj = 0; jj < 5; jj++) {
            int j = lane + jj * 64;
            float w = (j < OUTC) ? sW[k * OUTC + j] : 0.f;
#pragma unroll
            for (int n = 0; n < 4; n++) y[n][jj] = fmaf(zb[n], w, y[n][jj]);
        }
    }

#pragma unroll
    for (int n = 0; n < 4; n++) {
        float m = -1e30f;
#pragma unroll
        for (int jj = 0; jj < 5; jj++) {
            int j = lane + jj * 64;
            if (j < OUTC) m = fmaxf(m, y[n][jj]);
        }
#pragma unroll
        for (int o = 32; o > 0; o >>= 1) m = fmaxf(m, __shfl_xor(m, o));
        float s = 0.f;
#pragma unroll
        for (int jj = 0; jj < 5; jj++) {
            int j = lane + jj * 64;
            if (j < OUTC) s += __expf(y[n][jj] - m);
        }
#pragma unroll
        for (int o = 32; o > 0; o >>= 1) s += __shfl_xor(s, o);
        float lse = m + __logf(s);
#pragma unroll
        for (int jj = 0; jj < 5; jj++) {
            int j = lane + jj * 64;
            if (j < OUTC) {
                float v = y[n][jj] - lse;
                size_t ofs = (size_t)(i0 + n) * OUTC + j;
                if (flag) ((float*)outp)[ofs] = v;
                else      ((__hip_bfloat16*)outp)[ofs] = __float2bfloat16(v);
            }
        }
    }
}

extern "C" void kernel_launch(void* const* d_in, const int* in_sizes, int n_in,
                              void* d_out, int out_size, void* d_ws, size_t ws_size,
                              hipStream_t stream) {
    const void* x   = d_in[0];
    const int*  ei  = (const int*)d_in[1];
    const void* W1  = d_in[2];
    const void* b1  = d_in[3];
    const void* Wl1 = d_in[4];
    const void* bl1 = d_in[5];
    const void* W2  = d_in[6];
    const void* b2  = d_in[7];
    const void* Wl2 = d_in[8];
    const void* bl2 = d_in[9];
    const void* Wo  = d_in[10];
    const void* bo  = d_in[11];

    const int* srcp = ei;        // edge_index[0]
    const int* dstp = ei + EE;   // edge_index[1]

    // ws layout (4-byte words), 16B-aligned regions:
    //   A: words 960400..1360400 (bf16, 400000 words)
    //   B: words 1360400..1760400 (bf16, 400000 words)  -- DISJOINT (r7 bug: overlapped)
    char* wsb = (char*)d_ws;
    int*   flag    = (int*)wsb;                        // 0..3
    float* wc      = (float*)(wsb + 4 * 16);           // 16 .. 9788
    int*   cnt     = (int*)(wsb + 4 * 10000);          // .. 60000
    int*   off     = (int*)(wsb + 4 * 60000);          // .. 110001
    int*   bsum    = (int*)(wsb + 4 * 110004);
    int*   boff    = (int*)(wsb + 4 * 110208);
    int*   csr_src = (int*)(wsb + 4 * 110400);         // .. 910400
    float* dinv    = (float*)(wsb + 4 * 910400);       // .. 960400
    unsigned short* A = (unsigned short*)(wsb + 4 * 960400);   // bf16 rows, 1.6 MB
    unsigned short* B = (unsigned short*)(wsb + 4 * 1360400);  // bf16 rows, 1.6 MB

    const int gE = (EE + 255) / 256;
    const int gN = (NN + 255) / 256;
    const int gG = (NN * 64 + 255) / 256;   // wave-per-node gathers
    const int gW = (WC_TOT + 255) / 256;

    // dtype detect + weight conversion
    detect_kernel<<<1, 64, 0, stream>>>((const unsigned*)x, flag);
    convert_kernel<<<gW, 256, 0, stream>>>(W1, Wl1, b1, bl1, W2, Wl2, b2, bl2,
                                           Wo, bo, flag, wc);

    // CSR build + dinv (hierarchical scan; scan3 zeroes the cursor)
    hipMemsetAsync(cnt, 0, NN * sizeof(int), stream);
    count_kernel<<<gE, 256, 0, stream>>>(dstp, cnt);
    scan1_kernel<<<SB, 256, 0, stream>>>(cnt, off, bsum);
    scan2_kernel<<<1, 256, 0, stream>>>(bsum, boff);
    scan3_kernel<<<SB, 256, 0, stream>>>(cnt, off, boff, dinv);
    place_kernel<<<gE, 256, 0, stream>>>(srcp, dstp, off, cnt, csr_src);

    // layer 1: lin -> gather+combine (B <- h1)
    lin1_kernel<<<gN, 256, 0, stream>>>(x, wc, dinv, flag, A, B);
    gather_combine_kernel<<<gG, 256, 0, stream>>>(off, csr_src, dinv, A, B, wc + B1_OFF, 0);

    // layer 2: lin -> gather+combine (B <- out2*dinv)
    lin2_kernel<<<gN, 256, 0, stream>>>(B, wc, dinv, A);
    gather_combine_kernel<<<gG, 256, 0, stream>>>(off, csr_src, dinv, A, B, wc + B2_OFF, 1);

    // output aggregation: A <- z = dinv*(agg(B) + B)
    gather_combine_kernel<<<gG, 256, 0, stream>>>(off, csr_src, dinv, B, A, wc + B2_OFF, 2);

    // final matmul + log_softmax (streaming, 4-node-batched)
    final_kernel<<<(NN + 15) / 16, 256, 0, stream>>>(A, wc, flag, d_out);
}

// Round 9
// 251.426 us; speedup vs baseline: 1.2686x; 1.2417x over previous
//
#include <hip/hip_runtime.h>
#include <hip/hip_bf16.h>

#define NN   50000
#define EE   800000
#define INF_ 128
#define HH   16
#define OUTC 300

#define NB   196      // dst buckets: dst>>8, 196*256 = 50176 >= NN
#define CAP  4608     // max edges/bucket (mean 4096, sigma 64 -> 8-sigma headroom)
#define CHK  4096     // edges per bplace block
#define GB_  196      // bplace grid: 196*4096 = 802816 >= EE

// converted-weight offsets (words) inside wc
#define W1_OFF   0
#define WL1_OFF  2048
#define B1_OFF   4096
#define BL1_OFF  4112
#define W2_OFF   4128
#define WL2_OFF  4384
#define B2_OFF   4640
#define BL2_OFF  4656
#define WO_OFF   4672
#define BO_OFF   9472
#define WC_TOT   9772

__device__ __forceinline__ float bfu2f(unsigned short u) {
    return __uint_as_float(((unsigned)u) << 16);
}
__device__ __forceinline__ unsigned short f2bfu(float f) {
    __hip_bfloat16 h = __float2bfloat16(f);
    return *reinterpret_cast<unsigned short*>(&h);
}
__device__ __forceinline__ unsigned packbf(float lo, float hi) {
    return (unsigned)f2bfu(lo) | ((unsigned)f2bfu(hi) << 16);
}
__device__ __forceinline__ float cvt1(const void* p, int i, int flag) {
    return flag ? ((const float*)p)[i] : bfu2f(((const unsigned short*)p)[i]);
}

// ---- dtype detect ----
__global__ __launch_bounds__(64) void detect_kernel(const unsigned* __restrict__ xw, int* __restrict__ flag) {
    int t = threadIdx.x;
    int hits = 0;
#pragma unroll
    for (int q = 0; q < 4; q++) {
        unsigned w = xw[t * 4 + q];
        float lo = __uint_as_float(w << 16);
        if (!(fabsf(lo) < 1e4f)) hits++;
    }
#pragma unroll
    for (int o = 32; o > 0; o >>= 1) hits += __shfl_xor(hits, o);
    if (t == 0) flag[0] = (hits > 8) ? 1 : 0;   // 1 => inputs are fp32
}

// ---- convert all weights/biases to fp32 in ws ----
__global__ __launch_bounds__(256) void convert_kernel(
    const void* __restrict__ W1, const void* __restrict__ Wl1,
    const void* __restrict__ b1, const void* __restrict__ bl1,
    const void* __restrict__ W2, const void* __restrict__ Wl2,
    const void* __restrict__ b2, const void* __restrict__ bl2,
    const void* __restrict__ Wo, const void* __restrict__ bo,
    const int* __restrict__ flagp, float* __restrict__ wc)
{
    int t = blockIdx.x * 256 + threadIdx.x;
    if (t >= WC_TOT) return;
    const int flag = flagp[0];
    float v;
    if      (t < WL1_OFF) v = cvt1(W1,  t - W1_OFF,  flag);
    else if (t < B1_OFF)  v = cvt1(Wl1, t - WL1_OFF, flag);
    else if (t < BL1_OFF) v = cvt1(b1,  t - B1_OFF,  flag);
    else if (t < W2_OFF)  v = cvt1(bl1, t - BL1_OFF, flag);
    else if (t < WL2_OFF) v = cvt1(W2,  t - W2_OFF,  flag);
    else if (t < B2_OFF)  v = cvt1(Wl2, t - WL2_OFF, flag);
    else if (t < BL2_OFF) v = cvt1(b2,  t - B2_OFF,  flag);
    else if (t < WO_OFF)  v = cvt1(bl2, t - BL2_OFF, flag);
    else if (t < BO_OFF)  v = cvt1(Wo,  t - WO_OFF,  flag);
    else                  v = cvt1(bo,  t - BO_OFF,  flag);
    wc[t] = v;
}

// ---- stage 1: LDS multisplit of edges into 196 dst-buckets ----
__global__ __launch_bounds__(256) void bplace_kernel(
    const int* __restrict__ src, const int* __restrict__ dst,
    int* __restrict__ gcur, uint2* __restrict__ gpairs)
{
    __shared__ uint2 raw[CHK];            // 32 KB
    __shared__ uint2 srt[CHK];            // 32 KB
    __shared__ unsigned char bid[CHK];    // 4 KB
    __shared__ int cnt[NB];
    __shared__ int loff[NB];
    __shared__ int cur2[NB];
    __shared__ int gbase[NB];
    __shared__ int sc[256];

    int tid = threadIdx.x;
    int e0 = blockIdx.x * CHK;
    int n = min(CHK, EE - e0);
    if (n <= 0) return;
    for (int t = tid; t < NB; t += 256) cnt[t] = 0;
    __syncthreads();

    // load + bucket histogram
    for (int j = tid; j < n; j += 256) {
        unsigned s = (unsigned)src[e0 + j];
        unsigned d = (unsigned)dst[e0 + j];
        raw[j] = make_uint2(s, d);
        atomicAdd(&cnt[d >> 8], 1);
    }
    __syncthreads();

    // exclusive scan of cnt -> loff
    int v = (tid < NB) ? cnt[tid] : 0;
    sc[tid] = v;
    __syncthreads();
    for (int d = 1; d < 256; d <<= 1) {
        int u = (tid >= d) ? sc[tid - d] : 0;
        __syncthreads();
        sc[tid] += u;
        __syncthreads();
    }
    if (tid < NB) { loff[tid] = sc[tid] - v; cur2[tid] = sc[tid] - v; }
    __syncthreads();

    // scatter into bucket-sorted LDS order
    for (int j = tid; j < n; j += 256) {
        uint2 p = raw[j];
        int b = (int)(p.y >> 8);
        int pos = atomicAdd(&cur2[b], 1);
        srt[pos] = p;
        bid[pos] = (unsigned char)b;
    }
    __syncthreads();

    // reserve global space per bucket
    if (tid < NB) {
        int c = cnt[tid];
        gbase[tid] = c ? atomicAdd(&gcur[tid], c) : 0;
    }
    __syncthreads();

    // contiguous run copy to global bucket regions
    for (int j = tid; j < n; j += 256) {
        int b = bid[j];
        int p = gbase[b] + (j - loff[b]);
        if (p < CAP) gpairs[(size_t)b * CAP + p] = srt[j];
    }
}

// ---- stage 1.5: scan bucket totals -> gboff, set off[NN] ----
__global__ __launch_bounds__(256) void bscan_kernel(
    const int* __restrict__ gcur, int* __restrict__ gboff, int* __restrict__ off)
{
    __shared__ int sc[256];
    int t = threadIdx.x;
    int v = (t < NB) ? gcur[t] : 0;
    sc[t] = v;
    __syncthreads();
    for (int d = 1; d < 256; d <<= 1) {
        int u = (t >= d) ? sc[t - d] : 0;
        __syncthreads();
        sc[t] += u;
        __syncthreads();
    }
    if (t < NB) gboff[t] = sc[t] - v;
    if (t == 0) { gboff[NB] = EE; off[NN] = EE; }
}

// ---- stage 2: per-bucket node hist + scan + CSR placement + off/dinv ----
__global__ __launch_bounds__(256) void cplace_kernel(
    const uint2* __restrict__ gpairs, const int* __restrict__ gcur,
    const int* __restrict__ gboff, int* __restrict__ off,
    float* __restrict__ dinv, int* __restrict__ csr_src)
{
    __shared__ uint2 pl[CAP];     // 36 KB
    __shared__ int ncnt[256];
    __shared__ int nscan[256];
    __shared__ int noff[256];
    __shared__ int ncur[256];
    int b = blockIdx.x, t = threadIdx.x;
    int c = min(gcur[b], CAP);
    int gb = gboff[b];
    int nb = b << 8;

    ncnt[t] = 0;
    for (int j = t; j < c; j += 256) pl[j] = gpairs[(size_t)b * CAP + j];
    __syncthreads();

    for (int j = t; j < c; j += 256) atomicAdd(&ncnt[pl[j].y & 255], 1);
    __syncthreads();

    int v = ncnt[t];
    nscan[t] = v;
    __syncthreads();
    for (int d = 1; d < 256; d <<= 1) {
        int u = (t >= d) ? nscan[t - d] : 0;
        __syncthreads();
        nscan[t] += u;
        __syncthreads();
    }
    int excl = nscan[t] - v;
    noff[t] = excl;
    ncur[t] = excl;

    int node = nb + t;
    if (node < NN) {
        off[node] = gb + excl;
        dinv[node] = rsqrtf((float)v + 1.0f);
    }
    __syncthreads();

    for (int j = t; j < c; j += 256) {
        uint2 p = pl[j];
        int d = (int)(p.y & 255);
        int pos = atomicAdd(&ncur[d], 1);
        csr_src[gb + pos] = (int)p.x;
    }
}

// ---- layer1 linear: A = bf16((x@W1)*dinv), B = bf16(x@Wl1 + bl1) ----
__global__ __launch_bounds__(256) void lin1_kernel(
    const void* __restrict__ xp, const float* __restrict__ wc,
    const float* __restrict__ dinv, const int* __restrict__ flagp,
    unsigned short* __restrict__ A, unsigned short* __restrict__ B)
{
    __shared__ float2 sWL[INF_ * HH];   // .x = W1, .y = Wl1
    __shared__ float sb[HH];
    for (int t = threadIdx.x; t < INF_ * HH; t += 256)
        sWL[t] = make_float2(wc[W1_OFF + t], wc[WL1_OFF + t]);
    if (threadIdx.x < HH) sb[threadIdx.x] = wc[BL1_OFF + threadIdx.x];
    __syncthreads();

    int i = blockIdx.x * 256 + threadIdx.x;
    if (i >= NN) return;
    const int flag = flagp[0];

    float a[HH], l[HH];
#pragma unroll
    for (int f = 0; f < HH; f++) { a[f] = 0.f; l[f] = 0.f; }

    for (int k0 = 0; k0 < INF_ / 8; k0++) {
        float xv[8];
        if (flag) {
            const float4* xr = (const float4*)((const float*)xp + (size_t)i * INF_);
            float4 r0 = xr[k0 * 2], r1 = xr[k0 * 2 + 1];
            xv[0] = r0.x; xv[1] = r0.y; xv[2] = r0.z; xv[3] = r0.w;
            xv[4] = r1.x; xv[5] = r1.y; xv[6] = r1.z; xv[7] = r1.w;
        } else {
            const uint4* xr = (const uint4*)((const unsigned short*)xp + (size_t)i * INF_);
            uint4 v = xr[k0];
            unsigned uu[4] = { v.x, v.y, v.z, v.w };
#pragma unroll
            for (int q = 0; q < 4; q++) {
                xv[q * 2]     = __uint_as_float(uu[q] << 16);
                xv[q * 2 + 1] = __uint_as_float(uu[q] & 0xffff0000u);
            }
        }
#pragma unroll
        for (int j = 0; j < 8; j++) {
            float xj = xv[j];
            int k = k0 * 8 + j;
#pragma unroll
            for (int f = 0; f < HH; f++) {
                float2 wv = sWL[k * HH + f];
                a[f] = fmaf(xj, wv.x, a[f]);
                l[f] = fmaf(xj, wv.y, l[f]);
            }
        }
    }
    float di = dinv[i];
    unsigned pa[8], pb[8];
#pragma unroll
    for (int h = 0; h < 8; h++) {
        pa[h] = packbf(a[2 * h] * di, a[2 * h + 1] * di);
        pb[h] = packbf(l[2 * h] + sb[2 * h], l[2 * h + 1] + sb[2 * h + 1]);
    }
    uint4* Ar = (uint4*)(A + (size_t)i * HH);
    uint4* Br = (uint4*)(B + (size_t)i * HH);
    Ar[0] = make_uint4(pa[0], pa[1], pa[2], pa[3]);
    Ar[1] = make_uint4(pa[4], pa[5], pa[6], pa[7]);
    Br[0] = make_uint4(pb[0], pb[1], pb[2], pb[3]);
    Br[1] = make_uint4(pb[4], pb[5], pb[6], pb[7]);
}

// ---- fused gather + combine on bf16 rows (32 B/row) ----
// mode 0: Y[i] = bf16( relu(di*(agg + X[i]) + b) + Y[i] )
// mode 1: Y[i] = bf16( (relu(di*(agg + X[i]) + b) + Y[i]) * di )
// mode 2: Y[i] = bf16( di*(agg + X[i]) )
__global__ __launch_bounds__(256) void gather_combine_kernel(
    const int* __restrict__ off, const int* __restrict__ csr,
    const float* __restrict__ dinv, const unsigned short* __restrict__ X,
    unsigned short* __restrict__ Y, const float* __restrict__ bias, int mode)
{
    int wid = (blockIdx.x * 256 + threadIdx.x) >> 6;   // node id
    int lane = threadIdx.x & 63;
    if (wid >= NN) return;
    int e = lane >> 2, q = lane & 3;
    int s0 = off[wid], s1 = off[wid + 1];
    float a0 = 0.f, a1 = 0.f, a2 = 0.f, a3 = 0.f;
    for (int base = s0; base < s1; base += 16) {
        int p = base + e;
        bool valid = (p < s1);
        int s = valid ? csr[p] : 0;
        uint2 v = ((const uint2*)X)[(size_t)s * 4 + q];   // 8 B of 32 B row
        if (valid) {
            a0 += __uint_as_float(v.x << 16);
            a1 += __uint_as_float(v.x & 0xffff0000u);
            a2 += __uint_as_float(v.y << 16);
            a3 += __uint_as_float(v.y & 0xffff0000u);
        }
    }
#pragma unroll
    for (int m = 4; m <= 32; m <<= 1) {
        a0 += __shfl_xor(a0, m);
        a1 += __shfl_xor(a1, m);
        a2 += __shfl_xor(a2, m);
        a3 += __shfl_xor(a3, m);
    }
    if (lane < 4) {    // lane == q: features q*4 .. q*4+3
        float di = dinv[wid];
        uint2 xv = ((const uint2*)X)[(size_t)wid * 4 + lane];
        float x0 = __uint_as_float(xv.x << 16);
        float x1 = __uint_as_float(xv.x & 0xffff0000u);
        float x2 = __uint_as_float(xv.y << 16);
        float x3 = __uint_as_float(xv.y & 0xffff0000u);
        float o0, o1, o2, o3;
        if (mode == 2) {
            o0 = di * (a0 + x0); o1 = di * (a1 + x1);
            o2 = di * (a2 + x2); o3 = di * (a3 + x3);
        } else {
            uint2 yv = ((const uint2*)Y)[(size_t)wid * 4 + lane];
            float y0 = __uint_as_float(yv.x << 16);
            float y1 = __uint_as_float(yv.x & 0xffff0000u);
            float y2 = __uint_as_float(yv.y << 16);
            float y3 = __uint_as_float(yv.y & 0xffff0000u);
            o0 = fmaxf(di * (a0 + x0) + bias[lane * 4 + 0], 0.f) + y0;
            o1 = fmaxf(di * (a1 + x1) + bias[lane * 4 + 1], 0.f) + y1;
            o2 = fmaxf(di * (a2 + x2) + bias[lane * 4 + 2], 0.f) + y2;
            o3 = fmaxf(di * (a3 + x3) + bias[lane * 4 + 3], 0.f) + y3;
            if (mode) { o0 *= di; o1 *= di; o2 *= di; o3 *= di; }
        }
        ((uint2*)Y)[(size_t)wid * 4 + lane] = make_uint2(packbf(o0, o1), packbf(o2, o3));
    }
}

// ---- layer2 linear ----
__global__ __launch_bounds__(256) void lin2_kernel(
    unsigned short* __restrict__ B, const float* __restrict__ wc,
    const float* __restrict__ dinv, unsigned short* __restrict__ A)
{
    __shared__ float2 sWL[HH * HH];
    __shared__ float sb[HH];
    for (int t = threadIdx.x; t < HH * HH; t += 256)
        sWL[t] = make_float2(wc[W2_OFF + t], wc[WL2_OFF + t]);
    if (threadIdx.x < HH) sb[threadIdx.x] = wc[BL2_OFF + threadIdx.x];
    __syncthreads();

    int i = blockIdx.x * 256 + threadIdx.x;
    if (i >= NN) return;

    float z[HH];
    const uint4* br = (const uint4*)(B + (size_t)i * HH);
    uint4 r0 = br[0], r1 = br[1];
    unsigned uu[8] = { r0.x, r0.y, r0.z, r0.w, r1.x, r1.y, r1.z, r1.w };
#pragma unroll
    for (int h = 0; h < 8; h++) {
        z[2 * h]     = __uint_as_float(uu[h] << 16);
        z[2 * h + 1] = __uint_as_float(uu[h] & 0xffff0000u);
    }
    float a[HH], l[HH];
#pragma unroll
    for (int f = 0; f < HH; f++) { a[f] = 0.f; l[f] = 0.f; }
#pragma unroll
    for (int k = 0; k < HH; k++) {
        float zk = z[k];
#pragma unroll
        for (int f = 0; f < HH; f++) {
            float2 wv = sWL[k * HH + f];
            a[f] = fmaf(zk, wv.x, a[f]);
            l[f] = fmaf(zk, wv.y, l[f]);
        }
    }
    float di = dinv[i];
    unsigned pa[8], pb[8];
#pragma unroll
    for (int h = 0; h < 8; h++) {
        pa[h] = packbf(a[2 * h] * di, a[2 * h + 1] * di);
        pb[h] = packbf(l[2 * h] + sb[2 * h], l[2 * h + 1] + sb[2 * h + 1]);
    }
    uint4* Ar = (uint4*)(A + (size_t)i * HH);
    uint4* Br = (uint4*)(B + (size_t)i * HH);
    Ar[0] = make_uint4(pa[0], pa[1], pa[2], pa[3]);
    Ar[1] = make_uint4(pa[4], pa[5], pa[6], pa[7]);
    Br[0] = make_uint4(pb[0], pb[1], pb[2], pb[3]);
    Br[1] = make_uint4(pb[4], pb[5], pb[6], pb[7]);
}

// ---- final (streaming, 4 nodes per wave): y = z@Wo + bo, log_softmax ----
__global__ __launch_bounds__(256) void final_kernel(
    const unsigned short* __restrict__ Z, const float* __restrict__ wc,
    const int* __restrict__ flagp, void* __restrict__ outp)
{
    __shared__ float sW[HH * OUTC];   // 19.2 KB
    __shared__ float sbb[OUTC];
    for (int t = threadIdx.x; t < HH * OUTC; t += 256) sW[t] = wc[WO_OFF + t];
    for (int t = threadIdx.x; t < OUTC; t += 256)      sbb[t] = wc[BO_OFF + t];
    __syncthreads();

    const int flag = flagp[0];
    int wave = threadIdx.x >> 6, lane = threadIdx.x & 63;
    int i0 = blockIdx.x * 16 + wave * 4;    // 3125 blocks * 16 = 50000 exact

    float zf[4];
#pragma unroll
    for (int n = 0; n < 4; n++) zf[n] = bfu2f(Z[(size_t)(i0 + n) * HH + (lane & 15)]);

    float y[4][5];
#pragma unroll
    for (int jj = 0; jj < 5; jj++) {
        int j = lane + jj * 64;
        float b = (j < OUTC) ? sbb[j] : 0.f;
#pragma unroll
        for (int n = 0; n < 4; n++) y[n][jj] = b;
    }

#pragma unroll
    for (int k = 0; k < HH; k++) {
        float zb[4];
#pragma unroll
        for (int n = 0; n < 4; n++) zb[n] = __shfl(zf[n], k);
#pragma unroll
        for (int jj = 0; jj < 5; jj++) {
            int j = lane + jj * 64;
            float w = (j < OUTC) ? sW[k * OUTC + j] : 0.f;
#pragma unroll
            for (int n = 0; n < 4; n++) y[n][jj] = fmaf(zb[n], w, y[n][jj]);
        }
    }

#pragma unroll
    for (int n = 0; n < 4; n++) {
        float m = -1e30f;
#pragma unroll
        for (int jj = 0; jj < 5; jj++) {
            int j = lane + jj * 64;
            if (j < OUTC) m = fmaxf(m, y[n][jj]);
        }
#pragma unroll
        for (int o = 32; o > 0; o >>= 1) m = fmaxf(m, __shfl_xor(m, o));
        float s = 0.f;
#pragma unroll
        for (int jj = 0; jj < 5; jj++) {
            int j = lane + jj * 64;
            if (j < OUTC) s += __expf(y[n][jj] - m);
        }
#pragma unroll
        for (int o = 32; o > 0; o >>= 1) s += __shfl_xor(s, o);
        float lse = m + __logf(s);
#pragma unroll
        for (int jj = 0; jj < 5; jj++) {
            int j = lane + jj * 64;
            if (j < OUTC) {
                float v = y[n][jj] - lse;
                size_t ofs = (size_t)(i0 + n) * OUTC + j;
                if (flag) ((float*)outp)[ofs] = v;
                else      ((__hip_bfloat16*)outp)[ofs] = __float2bfloat16(v);
            }
        }
    }
}

extern "C" void kernel_launch(void* const* d_in, const int* in_sizes, int n_in,
                              void* d_out, int out_size, void* d_ws, size_t ws_size,
                              hipStream_t stream) {
    const void* x   = d_in[0];
    const int*  ei  = (const int*)d_in[1];
    const void* W1  = d_in[2];
    const void* b1  = d_in[3];
    const void* Wl1 = d_in[4];
    const void* bl1 = d_in[5];
    const void* W2  = d_in[6];
    const void* b2  = d_in[7];
    const void* Wl2 = d_in[8];
    const void* bl2 = d_in[9];
    const void* Wo  = d_in[10];
    const void* bo  = d_in[11];

    const int* srcp = ei;        // edge_index[0]
    const int* dstp = ei + EE;   // edge_index[1]

    // ws layout (4-byte words), all regions 16B-aligned:
    char* wsb = (char*)d_ws;
    int*   flag    = (int*)wsb;                        // 0..3
    float* wc      = (float*)(wsb + 4 * 16);           // 16 .. 9788
    int*   gcur    = (int*)(wsb + 4 * 10000);          // 196
    int*   gboff   = (int*)(wsb + 4 * 10200);          // 197
    int*   off     = (int*)(wsb + 4 * 10400);          // NN+1 -> .. 60401
    int*   csr_src = (int*)(wsb + 4 * 60416);          // EE -> .. 860416
    float* dinv    = (float*)(wsb + 4 * 860416);       // NN -> .. 910416
    uint2* gpairs  = (uint2*)(wsb + 4 * 910416);       // NB*CAP*2 words -> .. 2716752
    unsigned short* A = (unsigned short*)(wsb + 4 * 2716752);  // bf16, 400000 words
    unsigned short* B = (unsigned short*)(wsb + 4 * 3116752);  // bf16, 400000 words

    const int gN = (NN + 255) / 256;
    const int gG = (NN * 64 + 255) / 256;   // wave-per-node gathers
    const int gW = (WC_TOT + 255) / 256;

    // dtype detect + weight conversion
    detect_kernel<<<1, 64, 0, stream>>>((const unsigned*)x, flag);
    convert_kernel<<<gW, 256, 0, stream>>>(W1, Wl1, b1, bl1, W2, Wl2, b2, bl2,
                                           Wo, bo, flag, wc);

    // CSR build via LDS multisplit (replaces count/scan1-3/place)
    hipMemsetAsync(gcur, 0, NB * sizeof(int), stream);
    bplace_kernel<<<GB_, 256, 0, stream>>>(srcp, dstp, gcur, gpairs);
    bscan_kernel<<<1, 256, 0, stream>>>(gcur, gboff, off);
    cplace_kernel<<<NB, 256, 0, stream>>>(gpairs, gcur, gboff, off, dinv, csr_src);

    // layer 1: lin -> gather+combine (B <- h1)
    lin1_kernel<<<gN, 256, 0, stream>>>(x, wc, dinv, flag, A, B);
    gather_combine_kernel<<<gG, 256, 0, stream>>>(off, csr_src, dinv, A, B, wc + B1_OFF, 0);

    // layer 2: lin -> gather+combine (B <- out2*dinv)
    lin2_kernel<<<gN, 256, 0, stream>>>(B, wc, dinv, A);
    gather_combine_kernel<<<gG, 256, 0, stream>>>(off, csr_src, dinv, A, B, wc + B2_OFF, 1);

    // output aggregation: A <- z = dinv*(agg(B) + B)
    gather_combine_kernel<<<gG, 256, 0, stream>>>(off, csr_src, dinv, B, A, wc + B2_OFF, 2);

    // final matmul + log_softmax (streaming, 4-node-batched)
    final_kernel<<<(NN + 15) / 16, 256, 0, stream>>>(A, wc, flag, d_out);
}

// Round 10
// 225.249 us; speedup vs baseline: 1.4161x; 1.1162x over previous
//
#include <hip/hip_runtime.h>
#include <hip/hip_bf16.h>

#define NN   50000
#define EE   800000
#define INF_ 128
#define HH   16
#define OUTC 300

#define NB   196      // dst buckets: dst>>8, 196*256 = 50176 >= NN
#define CAP  4608     // max edges/bucket (mean 4082, big headroom)
#define CHK  4096     // edges per bplace block
#define GB_  196      // bplace grid: 196*4096 = 802816 >= EE

// converted-weight offsets (words) inside wc
#define W1_OFF   0
#define WL1_OFF  2048
#define B1_OFF   4096
#define BL1_OFF  4112
#define W2_OFF   4128
#define WL2_OFF  4384
#define B2_OFF   4640
#define BL2_OFF  4656
#define WO_OFF   4672
#define BO_OFF   9472
#define WC_TOT   9772

__device__ __forceinline__ float bfu2f(unsigned short u) {
    return __uint_as_float(((unsigned)u) << 16);
}
__device__ __forceinline__ unsigned short f2bfu(float f) {
    __hip_bfloat16 h = __float2bfloat16(f);
    return *reinterpret_cast<unsigned short*>(&h);
}
__device__ __forceinline__ unsigned packbf(float lo, float hi) {
    return (unsigned)f2bfu(lo) | ((unsigned)f2bfu(hi) << 16);
}
__device__ __forceinline__ float cvt1(const void* p, int i, int flag) {
    return flag ? ((const float*)p)[i] : bfu2f(((const unsigned short*)p)[i]);
}

// ---- convert weights to fp32 in ws; embedded dtype-detect (per-block, redundant);
//      block 0 also publishes flag and zeroes gcur ----
__global__ __launch_bounds__(256) void convert_kernel(
    const void* __restrict__ W1, const void* __restrict__ Wl1,
    const void* __restrict__ b1, const void* __restrict__ bl1,
    const void* __restrict__ W2, const void* __restrict__ Wl2,
    const void* __restrict__ b2, const void* __restrict__ bl2,
    const void* __restrict__ Wo, const void* __restrict__ bo,
    const unsigned* __restrict__ xw, int* __restrict__ flagp,
    int* __restrict__ gcur, float* __restrict__ wc)
{
    __shared__ int shits;
    int tid = threadIdx.x;
    if (tid == 0) shits = 0;
    __syncthreads();
    unsigned w = xw[tid];                 // 256 words sampled
    float lo = __uint_as_float(w << 16);
    if (!(fabsf(lo) < 1e4f)) atomicAdd(&shits, 1);
    __syncthreads();
    const int flag = (shits > 8) ? 1 : 0; // 1 => fp32 inputs

    if (blockIdx.x == 0) {
        if (tid == 0) flagp[0] = flag;
        if (tid < NB) gcur[tid] = 0;
    }

    int t = blockIdx.x * 256 + tid;
    if (t >= WC_TOT) return;
    float v;
    if      (t < WL1_OFF) v = cvt1(W1,  t - W1_OFF,  flag);
    else if (t < B1_OFF)  v = cvt1(Wl1, t - WL1_OFF, flag);
    else if (t < BL1_OFF) v = cvt1(b1,  t - B1_OFF,  flag);
    else if (t < W2_OFF)  v = cvt1(bl1, t - BL1_OFF, flag);
    else if (t < WL2_OFF) v = cvt1(W2,  t - W2_OFF,  flag);
    else if (t < B2_OFF)  v = cvt1(Wl2, t - WL2_OFF, flag);
    else if (t < BL2_OFF) v = cvt1(b2,  t - B2_OFF,  flag);
    else if (t < WO_OFF)  v = cvt1(bl2, t - BL2_OFF, flag);
    else if (t < BO_OFF)  v = cvt1(Wo,  t - WO_OFF,  flag);
    else                  v = cvt1(bo,  t - BO_OFF,  flag);
    wc[t] = v;
}

// ---- stage 1: LDS multisplit of edges into 196 dst-buckets ----
__global__ __launch_bounds__(256) void bplace_kernel(
    const int* __restrict__ src, const int* __restrict__ dst,
    int* __restrict__ gcur, uint2* __restrict__ gpairs)
{
    __shared__ uint2 raw[CHK];            // 32 KB
    __shared__ uint2 srt[CHK];            // 32 KB
    __shared__ unsigned char bid[CHK];    // 4 KB
    __shared__ int cnt[NB];
    __shared__ int loff[NB];
    __shared__ int cur2[NB];
    __shared__ int gbase[NB];
    __shared__ int sc[256];

    int tid = threadIdx.x;
    int e0 = blockIdx.x * CHK;
    int n = min(CHK, EE - e0);
    if (n <= 0) return;
    for (int t = tid; t < NB; t += 256) cnt[t] = 0;
    __syncthreads();

    for (int j = tid; j < n; j += 256) {
        unsigned s = (unsigned)src[e0 + j];
        unsigned d = (unsigned)dst[e0 + j];
        raw[j] = make_uint2(s, d);
        atomicAdd(&cnt[d >> 8], 1);
    }
    __syncthreads();

    int v = (tid < NB) ? cnt[tid] : 0;
    sc[tid] = v;
    __syncthreads();
    for (int d = 1; d < 256; d <<= 1) {
        int u = (tid >= d) ? sc[tid - d] : 0;
        __syncthreads();
        sc[tid] += u;
        __syncthreads();
    }
    if (tid < NB) { loff[tid] = sc[tid] - v; cur2[tid] = sc[tid] - v; }
    __syncthreads();

    for (int j = tid; j < n; j += 256) {
        uint2 p = raw[j];
        int b = (int)(p.y >> 8);
        int pos = atomicAdd(&cur2[b], 1);
        srt[pos] = p;
        bid[pos] = (unsigned char)b;
    }
    __syncthreads();

    if (tid < NB) {
        int c = cnt[tid];
        gbase[tid] = c ? atomicAdd(&gcur[tid], c) : 0;
    }
    __syncthreads();

    for (int j = tid; j < n; j += 256) {
        int b = bid[j];
        int p = gbase[b] + (j - loff[b]);
        if (p < CAP) gpairs[(size_t)b * CAP + p] = srt[j];
    }
}

// ---- stage 2: per-bucket node hist + scan + CSR placement + off/dinv.
//      Embedded scan of the 196 bucket totals (redundant per block). ----
__global__ __launch_bounds__(256) void cplace_kernel(
    const uint2* __restrict__ gpairs, const int* __restrict__ gcur,
    int* __restrict__ off, float* __restrict__ dinv, int* __restrict__ csr_src)
{
    __shared__ uint2 pl[CAP];     // 36 KB
    __shared__ int sc[256];
    __shared__ int ncnt[256];
    __shared__ int nscan[256];
    __shared__ int ncur[256];
    int b = blockIdx.x, t = threadIdx.x;

    // redundant scan of bucket totals -> gb (exclusive prefix of bucket b)
    int bv = (t < NB) ? gcur[t] : 0;
    sc[t] = bv;
    __syncthreads();
    for (int d = 1; d < 256; d <<= 1) {
        int u = (t >= d) ? sc[t - d] : 0;
        __syncthreads();
        sc[t] += u;
        __syncthreads();
    }
    __shared__ int gb_s;
    if (t == b) gb_s = sc[t] - bv;
    if (b == 0 && t == 0) off[NN] = EE;
    ncnt[t] = 0;
    __syncthreads();
    int gb = gb_s;

    int c = min(gcur[b], CAP);
    int nb = b << 8;
    for (int j = t; j < c; j += 256) pl[j] = gpairs[(size_t)b * CAP + j];
    __syncthreads();

    for (int j = t; j < c; j += 256) atomicAdd(&ncnt[pl[j].y & 255], 1);
    __syncthreads();

    int v = ncnt[t];
    nscan[t] = v;
    __syncthreads();
    for (int d = 1; d < 256; d <<= 1) {
        int u = (t >= d) ? nscan[t - d] : 0;
        __syncthreads();
        nscan[t] += u;
        __syncthreads();
    }
    int excl = nscan[t] - v;
    ncur[t] = excl;

    int node = nb + t;
    if (node < NN) {
        off[node] = gb + excl;
        dinv[node] = rsqrtf((float)v + 1.0f);
    }
    __syncthreads();

    for (int j = t; j < c; j += 256) {
        uint2 p = pl[j];
        int d = (int)(p.y & 255);
        int pos = atomicAdd(&ncur[d], 1);
        csr_src[gb + pos] = (int)p.x;
    }
}

// ---- layer1 linear: A = bf16((x@W1)*dinv), B = bf16(x@Wl1 + bl1) ----
__global__ __launch_bounds__(256) void lin1_kernel(
    const void* __restrict__ xp, const float* __restrict__ wc,
    const float* __restrict__ dinv, const int* __restrict__ flagp,
    unsigned short* __restrict__ A, unsigned short* __restrict__ B)
{
    __shared__ float2 sWL[INF_ * HH];   // .x = W1, .y = Wl1
    __shared__ float sb[HH];
    for (int t = threadIdx.x; t < INF_ * HH; t += 256)
        sWL[t] = make_float2(wc[W1_OFF + t], wc[WL1_OFF + t]);
    if (threadIdx.x < HH) sb[threadIdx.x] = wc[BL1_OFF + threadIdx.x];
    __syncthreads();

    int i = blockIdx.x * 256 + threadIdx.x;
    if (i >= NN) return;
    const int flag = flagp[0];

    float a[HH], l[HH];
#pragma unroll
    for (int f = 0; f < HH; f++) { a[f] = 0.f; l[f] = 0.f; }

    for (int k0 = 0; k0 < INF_ / 8; k0++) {
        float xv[8];
        if (flag) {
            const float4* xr = (const float4*)((const float*)xp + (size_t)i * INF_);
            float4 r0 = xr[k0 * 2], r1 = xr[k0 * 2 + 1];
            xv[0] = r0.x; xv[1] = r0.y; xv[2] = r0.z; xv[3] = r0.w;
            xv[4] = r1.x; xv[5] = r1.y; xv[6] = r1.z; xv[7] = r1.w;
        } else {
            const uint4* xr = (const uint4*)((const unsigned short*)xp + (size_t)i * INF_);
            uint4 v = xr[k0];
            unsigned uu[4] = { v.x, v.y, v.z, v.w };
#pragma unroll
            for (int q = 0; q < 4; q++) {
                xv[q * 2]     = __uint_as_float(uu[q] << 16);
                xv[q * 2 + 1] = __uint_as_float(uu[q] & 0xffff0000u);
            }
        }
#pragma unroll
        for (int j = 0; j < 8; j++) {
            float xj = xv[j];
            int k = k0 * 8 + j;
#pragma unroll
            for (int f = 0; f < HH; f++) {
                float2 wv = sWL[k * HH + f];
                a[f] = fmaf(xj, wv.x, a[f]);
                l[f] = fmaf(xj, wv.y, l[f]);
            }
        }
    }
    float di = dinv[i];
    unsigned pa[8], pb[8];
#pragma unroll
    for (int h = 0; h < 8; h++) {
        pa[h] = packbf(a[2 * h] * di, a[2 * h + 1] * di);
        pb[h] = packbf(l[2 * h] + sb[2 * h], l[2 * h + 1] + sb[2 * h + 1]);
    }
    uint4* Ar = (uint4*)(A + (size_t)i * HH);
    uint4* Br = (uint4*)(B + (size_t)i * HH);
    Ar[0] = make_uint4(pa[0], pa[1], pa[2], pa[3]);
    Ar[1] = make_uint4(pa[4], pa[5], pa[6], pa[7]);
    Br[0] = make_uint4(pb[0], pb[1], pb[2], pb[3]);
    Br[1] = make_uint4(pb[4], pb[5], pb[6], pb[7]);
}

// ---- 4-nodes-per-wave gather + combine on bf16 rows (32 B/row).
// lane = n*16 + j (n: node in wave, j: 0..15). Phase 1: lane j loads csr entry
// j of its node's chunk. Phase 2: 4 rounds; round r, lane j handles edge
// e = r*4 + (j>>2) with row piece q = j&3 (8 B). All round addresses come from
// shuffles of the phase-1 data -> loads issue back-to-back (no serial rounds).
// mode 0: Y[i] = bf16( relu(di*(agg + X[i]) + b) + Y[i] )
// mode 1: Y[i] = bf16( (relu(di*(agg + X[i]) + b) + Y[i]) * di )
// mode 2: Y[i] = bf16( di*(agg + X[i]) )
__global__ __launch_bounds__(256) void gather_combine_kernel(
    const int* __restrict__ off, const int* __restrict__ csr,
    const float* __restrict__ dinv, const unsigned short* __restrict__ X,
    unsigned short* __restrict__ Y, const float* __restrict__ bias, int mode)
{
    int lane = threadIdx.x & 63;
    int w = (blockIdx.x * 256 + threadIdx.x) >> 6;   // wave id, 0..12499
    int n = lane >> 4, j = lane & 15;
    int node = w * 4 + n;                            // 12500*4 = NN exact
    int s0 = off[node], s1 = off[node + 1];
    int deg = s1 - s0;

    // wave-uniform chunk count: max deg over the wave's 4 nodes
    int wmax = deg;
    wmax = max(wmax, __shfl_xor(wmax, 16));
    wmax = max(wmax, __shfl_xor(wmax, 32));

    const uint2* X4 = (const uint2*)X;
    float a0 = 0.f, a1 = 0.f, a2 = 0.f, a3 = 0.f;
    int eh = j >> 2, q = j & 3;

    for (int base = 0; base < wmax; base += 16) {
        int p = s0 + base + j;
        int sj = (p < s1) ? csr[p] : 0;
#pragma unroll
        for (int r = 0; r < 4; r++) {
            int e = r * 4 + eh;
            int se = __shfl(sj, (n << 4) + e);        // src of edge e, node n
            bool val = (base + e) < deg;
            uint2 v = X4[(size_t)(val ? se : node) * 4 + q];
            if (val) {
                a0 += __uint_as_float(v.x << 16);
                a1 += __uint_as_float(v.x & 0xffff0000u);
                a2 += __uint_as_float(v.y << 16);
                a3 += __uint_as_float(v.y & 0xffff0000u);
            }
        }
    }
    // reduce across the 4 e-sublanes sharing (n,q): bits 2,3 of j
#pragma unroll
    for (int m = 4; m <= 8; m <<= 1) {
        a0 += __shfl_xor(a0, m);
        a1 += __shfl_xor(a1, m);
        a2 += __shfl_xor(a2, m);
        a3 += __shfl_xor(a3, m);
    }
    if (eh == 0) {    // lanes j = q: features q*4 .. q*4+3 of node
        float di = dinv[node];
        uint2 xv = X4[(size_t)node * 4 + q];
        float x0 = __uint_as_float(xv.x << 16);
        float x1 = __uint_as_float(xv.x & 0xffff0000u);
        float x2 = __uint_as_float(xv.y << 16);
        float x3 = __uint_as_float(xv.y & 0xffff0000u);
        float o0, o1, o2, o3;
        if (mode == 2) {
            o0 = di * (a0 + x0); o1 = di * (a1 + x1);
            o2 = di * (a2 + x2); o3 = di * (a3 + x3);
        } else {
            uint2 yv = ((const uint2*)Y)[(size_t)node * 4 + q];
            float y0 = __uint_as_float(yv.x << 16);
            float y1 = __uint_as_float(yv.x & 0xffff0000u);
            float y2 = __uint_as_float(yv.y << 16);
            float y3 = __uint_as_float(yv.y & 0xffff0000u);
            o0 = fmaxf(di * (a0 + x0) + bias[q * 4 + 0], 0.f) + y0;
            o1 = fmaxf(di * (a1 + x1) + bias[q * 4 + 1], 0.f) + y1;
            o2 = fmaxf(di * (a2 + x2) + bias[q * 4 + 2], 0.f) + y2;
            o3 = fmaxf(di * (a3 + x3) + bias[q * 4 + 3], 0.f) + y3;
            if (mode) { o0 *= di; o1 *= di; o2 *= di; o3 *= di; }
        }
        ((uint2*)Y)[(size_t)node * 4 + q] = make_uint2(packbf(o0, o1), packbf(o2, o3));
    }
}

// ---- layer2 linear ----
__global__ __launch_bounds__(256) void lin2_kernel(
    unsigned short* __restrict__ B, const float* __restrict__ wc,
    const float* __restrict__ dinv, unsigned short* __restrict__ A)
{
    __shared__ float2 sWL[HH * HH];
    __shared__ float sb[HH];
    for (int t = threadIdx.x; t < HH * HH; t += 256)
        sWL[t] = make_float2(wc[W2_OFF + t], wc[WL2_OFF + t]);
    if (threadIdx.x < HH) sb[threadIdx.x] = wc[BL2_OFF + threadIdx.x];
    __syncthreads();

    int i = blockIdx.x * 256 + threadIdx.x;
    if (i >= NN) return;

    float z[HH];
    const uint4* br = (const uint4*)(B + (size_t)i * HH);
    uint4 r0 = br[0], r1 = br[1];
    unsigned uu[8] = { r0.x, r0.y, r0.z, r0.w, r1.x, r1.y, r1.z, r1.w };
#pragma unroll
    for (int h = 0; h < 8; h++) {
        z[2 * h]     = __uint_as_float(uu[h] << 16);
        z[2 * h + 1] = __uint_as_float(uu[h] & 0xffff0000u);
    }
    float a[HH], l[HH];
#pragma unroll
    for (int f = 0; f < HH; f++) { a[f] = 0.f; l[f] = 0.f; }
#pragma unroll
    for (int k = 0; k < HH; k++) {
        float zk = z[k];
#pragma unroll
        for (int f = 0; f < HH; f++) {
            float2 wv = sWL[k * HH + f];
            a[f] = fmaf(zk, wv.x, a[f]);
            l[f] = fmaf(zk, wv.y, l[f]);
        }
    }
    float di = dinv[i];
    unsigned pa[8], pb[8];
#pragma unroll
    for (int h = 0; h < 8; h++) {
        pa[h] = packbf(a[2 * h] * di, a[2 * h + 1] * di);
        pb[h] = packbf(l[2 * h] + sb[2 * h], l[2 * h + 1] + sb[2 * h + 1]);
    }
    uint4* Ar = (uint4*)(A + (size_t)i * HH);
    uint4* Br = (uint4*)(B + (size_t)i * HH);
    Ar[0] = make_uint4(pa[0], pa[1], pa[2], pa[3]);
    Ar[1] = make_uint4(pa[4], pa[5], pa[6], pa[7]);
    Br[0] = make_uint4(pb[0], pb[1], pb[2], pb[3]);
    Br[1] = make_uint4(pb[4], pb[5], pb[6], pb[7]);
}

// ---- final (streaming, 4 nodes per wave): y = z@Wo + bo, log_softmax ----
__global__ __launch_bounds__(256) void final_kernel(
    const unsigned short* __restrict__ Z, const float* __restrict__ wc,
    const int* __restrict__ flagp, void* __restrict__ outp)
{
    __shared__ float sW[HH * OUTC];   // 19.2 KB
    __shared__ float sbb[OUTC];
    for (int t = threadIdx.x; t < HH * OUTC; t += 256) sW[t] = wc[WO_OFF + t];
    for (int t = threadIdx.x; t < OUTC; t += 256)      sbb[t] = wc[BO_OFF + t];
    __syncthreads();

    const int flag = flagp[0];
    int wave = threadIdx.x >> 6, lane = threadIdx.x & 63;
    int i0 = blockIdx.x * 16 + wave * 4;    // 3125 blocks * 16 = 50000 exact

    float zf[4];
#pragma unroll
    for (int n = 0; n < 4; n++) zf[n] = bfu2f(Z[(size_t)(i0 + n) * HH + (lane & 15)]);

    float y[4][5];
#pragma unroll
    for (int jj = 0; jj < 5; jj++) {
        int j = lane + jj * 64;
        float b = (j < OUTC) ? sbb[j] : 0.f;
#pragma unroll
        for (int n = 0; n < 4; n++) y[n][jj] = b;
    }

#pragma unroll
    for (int k = 0; k < HH; k++) {
        float zb[4];
#pragma unroll
        for (int n = 0; n < 4; n++) zb[n] = __shfl(zf[n], k);
#pragma unroll
        for (int jj = 0; jj < 5; jj++) {
            int j = lane + jj * 64;
            float w = (j < OUTC) ? sW[k * OUTC + j] : 0.f;
#pragma unroll
            for (int n = 0; n < 4; n++) y[n][jj] = fmaf(zb[n], w, y[n][jj]);
        }
    }

#pragma unroll
    for (int n = 0; n < 4; n++) {
        float m = -1e30f;
#pragma unroll
        for (int jj = 0; jj < 5; jj++) {
            int j = lane + jj * 64;
            if (j < OUTC) m = fmaxf(m, y[n][jj]);
        }
#pragma unroll
        for (int o = 32; o > 0; o >>= 1) m = fmaxf(m, __shfl_xor(m, o));
        float s = 0.f;
#pragma unroll
        for (int jj = 0; jj < 5; jj++) {
            int j = lane + jj * 64;
            if (j < OUTC) s += __expf(y[n][jj] - m);
        }
#pragma unroll
        for (int o = 32; o > 0; o >>= 1) s += __shfl_xor(s, o);
        float lse = m + __logf(s);
#pragma unroll
        for (int jj = 0; jj < 5; jj++) {
            int j = lane + jj * 64;
            if (j < OUTC) {
                float v = y[n][jj] - lse;
                size_t ofs = (size_t)(i0 + n) * OUTC + j;
                if (flag) ((float*)outp)[ofs] = v;
                else      ((__hip_bfloat16*)outp)[ofs] = __float2bfloat16(v);
            }
        }
    }
}

extern "C" void kernel_launch(void* const* d_in, const int* in_sizes, int n_in,
                              void* d_out, int out_size, void* d_ws, size_t ws_size,
                              hipStream_t stream) {
    const void* x   = d_in[0];
    const int*  ei  = (const int*)d_in[1];
    const void* W1  = d_in[2];
    const void* b1  = d_in[3];
    const void* Wl1 = d_in[4];
    const void* bl1 = d_in[5];
    const void* W2  = d_in[6];
    const void* b2  = d_in[7];
    const void* Wl2 = d_in[8];
    const void* bl2 = d_in[9];
    const void* Wo  = d_in[10];
    const void* bo  = d_in[11];

    const int* srcp = ei;        // edge_index[0]
    const int* dstp = ei + EE;   // edge_index[1]

    // ws layout (4-byte words), all regions 16B-aligned:
    char* wsb = (char*)d_ws;
    int*   flag    = (int*)wsb;                        // 0..3
    float* wc      = (float*)(wsb + 4 * 16);           // 16 .. 9788
    int*   gcur    = (int*)(wsb + 4 * 10000);          // 196
    int*   off     = (int*)(wsb + 4 * 10400);          // NN+1 -> .. 60401
    int*   csr_src = (int*)(wsb + 4 * 60416);          // EE -> .. 860416
    float* dinv    = (float*)(wsb + 4 * 860416);       // NN -> .. 910416
    uint2* gpairs  = (uint2*)(wsb + 4 * 910416);       // NB*CAP*2 words -> .. 2716752
    unsigned short* A = (unsigned short*)(wsb + 4 * 2716752);  // bf16, 400000 words
    unsigned short* B = (unsigned short*)(wsb + 4 * 3116752);  // bf16, 400000 words

    const int gN  = (NN + 255) / 256;
    const int gG4 = (NN / 4 * 64) / 256;    // 12500 waves -> 3125 blocks
    const int gW  = (WC_TOT + 255) / 256;

    // weights convert + dtype detect + gcur zero (fused)
    convert_kernel<<<gW, 256, 0, stream>>>(W1, Wl1, b1, bl1, W2, Wl2, b2, bl2,
                                           Wo, bo, (const unsigned*)x, flag, gcur, wc);

    // CSR build via LDS multisplit (bscan folded into cplace)
    bplace_kernel<<<GB_, 256, 0, stream>>>(srcp, dstp, gcur, gpairs);
    cplace_kernel<<<NB, 256, 0, stream>>>(gpairs, gcur, off, dinv, csr_src);

    // layer 1: lin -> gather+combine (B <- h1)
    lin1_kernel<<<gN, 256, 0, stream>>>(x, wc, dinv, flag, A, B);
    gather_combine_kernel<<<gG4, 256, 0, stream>>>(off, csr_src, dinv, A, B, wc + B1_OFF, 0);

    // layer 2: lin -> gather+combine (B <- out2*dinv)
    lin2_kernel<<<gN, 256, 0, stream>>>(B, wc, dinv, A);
    gather_combine_kernel<<<gG4, 256, 0, stream>>>(off, csr_src, dinv, A, B, wc + B2_OFF, 1);

    // output aggregation: A <- z = dinv*(agg(B) + B)
    gather_combine_kernel<<<gG4, 256, 0, stream>>>(off, csr_src, dinv, B, A, wc + B2_OFF, 2);

    // final matmul + log_softmax (streaming, 4-node-batched)
    final_kernel<<<gG4, 256, 0, stream>>>(A, wc, flag, d_out);
}